// Round 10
// baseline (112.276 us; speedup 1.0000x reference)
//
#include <hip/hip_runtime.h>
#include <stdint.h>

typedef uint16_t u16;
typedef __attribute__((ext_vector_type(8))) short    bf16x8;  // 8 bf16 (4 VGPRs)
typedef __attribute__((ext_vector_type(8))) uint16_t u16x8;
typedef __attribute__((ext_vector_type(4))) float    f32x4;

#define B_    2
#define N_    100000
#define K_    26
#define CIN_  32
#define COUT_ 32
#define MID2  50000                                  // node-range split
#define ZROW  (N_ + 1)                               // all-zero dummy row (hot line)

#define XT_ROWS  (N_ + 2)                            // + fill row (N_), + zero row (N_+1)
#define XT_BYTES ((size_t)B_ * XT_ROWS * CIN_ * 2)   // 12,800,256 bytes

// ---- prep kernel geometry (xt [B][N+2][32] bf16 64B rows, Wb [32][832] bf16) ----
#define TCHUNK      64
#define TBLK_PER_B  ((N_ + TCHUNK - 1) / TCHUNK)     // 1563
#define TBLKS       (B_ * TBLK_PER_B)                // 3126
#define WBLKS       13                               // 13 * 2048 = 26624 W elems
#define PREP_GRID   (TBLKS + 1 + WBLKS)

// ---- conv kernel geometry ----
// Grid 1024 x 256thr = 4 blocks/CU, ENTIRE grid co-resident -> passes stay
// roughly chip-aligned. Per batch: 512 blocks x 4 waves = 2048 waves;
// 3 contiguous 16-node tiles/wave = 6144 tiles; tail 106 tiles for waves w<106.
#define CONV_GRID   1024
#define WPB3        2048
#define TILES_PB    (N_ / 16)                        // 6250
#define TAIL        (TILES_PB - 3 * WPB3)            // 106

__device__ __forceinline__ u16 f2bf(float f) {
    union { float f; uint32_t u; } v; v.f = f;
    return (u16)((v.u + 0x7FFFu + ((v.u >> 16) & 1u)) >> 16);  // RNE
}

__global__ __launch_bounds__(256) void prep_kernel(
    const float* __restrict__ inp, const float* __restrict__ W,
    const float* __restrict__ fill, u16* __restrict__ xt, u16* __restrict__ Wb)
{
    int tid = threadIdx.x;
    int blk = blockIdx.x;
    if (blk >= TBLKS) {
        int job = blk - TBLKS;
        if (job == 0) {
            if (tid < 64) {                            // fill row at N_
                int b = tid >> 5, c = tid & 31;
                xt[((size_t)b * XT_ROWS + N_) * CIN_ + c] = f2bf(fill[c]);
            } else if (tid < 128) {                    // zero row at N_+1
                int t = tid - 64;
                int b = t >> 5, c = t & 31;
                xt[((size_t)b * XT_ROWS + ZROW) * CIN_ + c] = (u16)0;
            }
        } else {
            int base = (job - 1) * 2048 + tid * 8;    // exact: 13*2048 = 26624
            const float4* src = (const float4*)(W + base);
            float4 x = src[0], y = src[1];
            u16x8 o;
            o[0] = f2bf(x.x); o[1] = f2bf(x.y); o[2] = f2bf(x.z); o[3] = f2bf(x.w);
            o[4] = f2bf(y.x); o[5] = f2bf(y.y); o[6] = f2bf(y.z); o[7] = f2bf(y.w);
            *(u16x8*)(Wb + base) = o;
        }
        return;
    }
    __shared__ u16 tile[64][40];
    int b  = blk / TBLK_PER_B;
    int n0 = (blk % TBLK_PER_B) * TCHUNK;
    const float* inb = inp + (size_t)b * CIN_ * N_;
    #pragma unroll
    for (int it = 0; it < 8; ++it) {
        int idx = it * 256 + tid;
        int c = idx >> 6, n = idx & 63;
        if (n0 + n < N_) tile[n][c] = f2bf(inb[(size_t)c * N_ + n0 + n]);
    }
    __syncthreads();
    int n = tid >> 2, seg = tid & 3;
    if (n0 + n < N_) {
        u16x8 v = *(const u16x8*)&tile[n][seg * 8];
        *(u16x8*)(xt + ((size_t)b * XT_ROWS + n0 + n) * CIN_ + seg * 8) = v;
    }
}

#define MFMA16(a, b, c) __builtin_amdgcn_mfma_f32_16x16x32_bf16((a), (b), (c), 0, 0, 0)

// Gather + MFMA GEMM, node-range 2-pass for L2 residency of the gather table.
// Pass p touches only rows in its 50k half (3.2MB/(batch,pass) < 4MB XCD L2);
// out-of-range lanes gather the hot ZERO row (zero contribution, no masking).
// Indices in LDS (staged once), W from global with distance-2 prefetch,
// gathers distance-3 ring. acc static, fully unrolled (no scratch).
__global__ __launch_bounds__(256, 4) void conv_kernel(
    const u16* __restrict__ xt, const u16* __restrict__ Wb,
    const int* __restrict__ nbr, const float* __restrict__ bias,
    float* __restrict__ out)
{
    __shared__ int idxl[4][1248];                     // 3 tiles x 416 ints, per wave
    int tid = threadIdx.x, bid = blockIdx.x;
    int xcd = bid & 7, slot = bid >> 3;
    int b   = xcd >> 2;                               // batch -> XCD half
    int wv  = tid >> 6, lane = tid & 63;
    int l15 = lane & 15, g = lane >> 4;
    int w   = (slot * 4 + (xcd & 3)) * 4 + wv;        // wave id in batch [0,2048)

    const int* nbb  = nbr + (size_t)b * N_ * K_;
    float*     outb = out + (size_t)b * COUT_ * N_;
    const u16* xg   = xt + (size_t)b * XT_ROWS * CIN_ + (g << 3);
    const u16* wgA  = Wb + l15 * 832 + (g << 3);      // o = l15 row

    // ---- stage 3 tiles' indices (1248 contiguous ints) into LDS ----
    {
        const int* src = nbb + (size_t)w * 1248;
        int* dst = idxl[wv];
        #pragma unroll
        for (int r = 0; r < 19; ++r) dst[r * 64 + lane] = src[r * 64 + lane];
        if (lane < 32) dst[19 * 64 + lane] = src[19 * 64 + lane];
    }
    const int* q = &idxl[wv][l15 * 26];               // + j*416 + k

    f32x4 acc[3][2];
    #pragma unroll
    for (int j = 0; j < 3; ++j) { acc[j][0] = 0.0f; acc[j][1] = 0.0f; }

    #pragma unroll
    for (int p = 0; p < 2; ++p) {
        bf16x8 f[4][3];                               // gather ring, distance 3
        int    ixc[3];                                // idx feeding next gather trio
        bf16x8 wAc, wBc, wAn, wBn;

        #pragma unroll
        for (int kk = 0; kk < 3; ++kk)
            #pragma unroll
            for (int j = 0; j < 3; ++j) {
                int ix = q[j * 416 + kk];
                bool in = p ? (ix >= MID2) : (ix < MID2);
                uint32_t ia = in ? (uint32_t)ix : (uint32_t)ZROW;
                f[kk][j] = *(const bf16x8*)(xg + ((size_t)ia << 5));
            }
        #pragma unroll
        for (int j = 0; j < 3; ++j) ixc[j] = q[j * 416 + 3];
        wAc = *(const bf16x8*)(wgA);
        wBc = *(const bf16x8*)(wgA + 16 * 832);
        wAn = *(const bf16x8*)(wgA + 32);
        wBn = *(const bf16x8*)(wgA + 16 * 832 + 32);
        __builtin_amdgcn_sched_barrier(0);

        #pragma unroll
        for (int k = 0; k < 26; ++k) {
            int ixn[3];
            if (k < 22) {                             // idx for gathers at k+4
                #pragma unroll
                for (int j = 0; j < 3; ++j) ixn[j] = q[j * 416 + k + 4];
            }
            if (k < 23) {                             // gathers for k+3
                #pragma unroll
                for (int j = 0; j < 3; ++j) {
                    int ix = ixc[j];
                    bool in = p ? (ix >= MID2) : (ix < MID2);
                    uint32_t ia = in ? (uint32_t)ix : (uint32_t)ZROW;
                    f[(k + 3) & 3][j] = *(const bf16x8*)(xg + ((size_t)ia << 5));
                }
            }
            bf16x8 wAf, wBf;
            if (k < 24) {                             // W(k+2) in flight
                wAf = *(const bf16x8*)(wgA + (k + 2) * 32);
                wBf = *(const bf16x8*)(wgA + 16 * 832 + (k + 2) * 32);
            } else { wAf = wAn; wBf = wBn; }
            __builtin_amdgcn_sched_barrier(0);        // pin issue block above MFMAs
            #pragma unroll
            for (int j = 0; j < 3; ++j) {
                acc[j][0] = MFMA16(wAc, f[k & 3][j], acc[j][0]);
                acc[j][1] = MFMA16(wBc, f[k & 3][j], acc[j][1]);
            }
            wAc = wAn; wBc = wBn; wAn = wAf; wBn = wBf;
            if (k < 22) {
                #pragma unroll
                for (int j = 0; j < 3; ++j) ixc[j] = ixn[j];
            }
        }
        __syncthreads();                              // align block at pass boundary
    }

    // ---- epilogue: D col = l15 -> node, D row = g*4+r -> o ----
    #pragma unroll
    for (int j = 0; j < 3; ++j) {
        int node = (w * 3 + j) * 16 + l15;
        #pragma unroll
        for (int r = 0; r < 4; ++r) {
            outb[(size_t)(g * 4 + r) * N_ + node]      = acc[j][0][r] + bias[g * 4 + r];
            outb[(size_t)(g * 4 + r + 16) * N_ + node] = acc[j][1][r] + bias[g * 4 + r + 16];
        }
    }

    // ---- tail: 106 extra tiles per batch, single-pass 13-deep (R8 style) ----
    if (w < TAIL) {
        int t = 3 * WPB3 + w;
        const int* qp = nbb + ((size_t)t * 16 + l15) * K_;
        f32x4 c0 = 0.0f, c1 = 0.0f;
        bf16x8 tf[13];
        #pragma unroll
        for (int k = 0; k < 13; ++k)
            tf[k] = *(const bf16x8*)(xg + ((size_t)(uint32_t)qp[k] << 5));
        __builtin_amdgcn_sched_barrier(0);
        #pragma unroll
        for (int k = 0; k < 13; ++k) {
            bf16x8 a0 = *(const bf16x8*)(wgA + k * 32);
            bf16x8 a1 = *(const bf16x8*)(wgA + 16 * 832 + k * 32);
            int qn = qp[13 + k];
            c0 = MFMA16(a0, tf[k], c0);
            c1 = MFMA16(a1, tf[k], c1);
            tf[k] = *(const bf16x8*)(xg + ((size_t)(uint32_t)qn << 5));
        }
        __builtin_amdgcn_sched_barrier(0);
        #pragma unroll
        for (int k = 0; k < 13; ++k) {
            bf16x8 a0 = *(const bf16x8*)(wgA + (13 + k) * 32);
            bf16x8 a1 = *(const bf16x8*)(wgA + 16 * 832 + (13 + k) * 32);
            c0 = MFMA16(a0, tf[k], c0);
            c1 = MFMA16(a1, tf[k], c1);
        }
        int node = t * 16 + l15;
        #pragma unroll
        for (int r = 0; r < 4; ++r) {
            outb[(size_t)(g * 4 + r) * N_ + node]      = c0[r] + bias[g * 4 + r];
            outb[(size_t)(g * 4 + r + 16) * N_ + node] = c1[r] + bias[g * 4 + r + 16];
        }
    }
}

extern "C" void kernel_launch(void* const* d_in, const int* in_sizes, int n_in,
                              void* d_out, int out_size, void* d_ws, size_t ws_size,
                              hipStream_t stream) {
    (void)in_sizes; (void)n_in; (void)out_size; (void)ws_size;
    const float* inp  = (const float*)d_in[0];
    const int*   nbr  = (const int*)d_in[1];
    const float* W    = (const float*)d_in[2];
    const float* bias = (const float*)d_in[3];
    const float* fill = (const float*)d_in[4];
    float* out = (float*)d_out;

    u16* xt = (u16*)d_ws;                              // [B][N+2][32] bf16
    u16* Wb = (u16*)((char*)d_ws + XT_BYTES);          // [32][832] bf16

    prep_kernel<<<PREP_GRID, 256, 0, stream>>>(inp, W, fill, xt, Wb);
    conv_kernel<<<CONV_GRID, 256, 0, stream>>>(xt, Wb, nbr, bias, out);
}